// Round 15
// baseline (734.990 us; speedup 1.0000x reference)
//
#include <hip/hip_runtime.h>
#include <math.h>

#define NBLK 256
#define NTHR 1024

// ---- ws layout ----
// uints: [b*16] arrival flags (b<256); [4096] gen; [4112 + (rt*8+kc)*16] rt-flags
// floats from 8256:
#define OFF_OBS     8256        // 8192    (cached, immutable after init barrier)
#define OFF_PART    16448       // 524288  (BYPASS domain: write+read-once, no reuse)
#define OFF_WTPOOL  540736      // 262144  (cached immutable)
#define OFF_WTG_E   802880      // 163840  (cached immutable)
#define OFF_WTG_D   966720      // 163840  (cached immutable)
#define OFF_HSBUF   1130560     // (nstep+1) * 65536 -- rotated hs buffers (write-once)

#define LDS_BYTES 31232

typedef float vf4 __attribute__((ext_vector_type(4)));
typedef float vf2 __attribute__((ext_vector_type(2)));

// Swizzled AsT row offset: row*20 + 4-float pad every 32 rows (bank-tiling, r13).
__device__ __forceinline__ int asr20(int row) { return row * 20 + ((row >> 5) << 2); }

// ---------- L2-bypass (LLC-coherent) access ----------
__device__ __forceinline__ void st_bypass_f4(float* p, vf4 v) {
    asm volatile("global_store_dwordx4 %0, %1, off sc0 sc1" :: "v"(p), "v"(v) : "memory");
}
__device__ __forceinline__ void st_bypass_f2(float* p, vf2 v) {
    asm volatile("global_store_dwordx2 %0, %1, off sc0 sc1" :: "v"(p), "v"(v) : "memory");
}
__device__ __forceinline__ void ld_bypass_f4x8(const float* b, int stride, vf4* v) {
    asm volatile(
        "global_load_dwordx4 %0, %8, off sc0 sc1\n\t"
        "global_load_dwordx4 %1, %9, off sc0 sc1\n\t"
        "global_load_dwordx4 %2, %10, off sc0 sc1\n\t"
        "global_load_dwordx4 %3, %11, off sc0 sc1\n\t"
        "global_load_dwordx4 %4, %12, off sc0 sc1\n\t"
        "global_load_dwordx4 %5, %13, off sc0 sc1\n\t"
        "global_load_dwordx4 %6, %14, off sc0 sc1\n\t"
        "global_load_dwordx4 %7, %15, off sc0 sc1\n\t"
        "s_waitcnt vmcnt(0)"
        : "=&v"(v[0]), "=&v"(v[1]), "=&v"(v[2]), "=&v"(v[3]),
          "=&v"(v[4]), "=&v"(v[5]), "=&v"(v[6]), "=&v"(v[7])
        : "v"(b), "v"(b + stride), "v"(b + 2 * stride), "v"(b + 3 * stride),
          "v"(b + 4 * stride), "v"(b + 5 * stride), "v"(b + 6 * stride), "v"(b + 7 * stride)
        : "memory");
}

// Fenced barrier (init only).
__device__ __forceinline__ void grid_barrier_fenced(unsigned* flags, unsigned* gen, unsigned seq) {
    __syncthreads();
    if (threadIdx.x == 0)
        __builtin_amdgcn_fence(__ATOMIC_RELEASE, "agent");
    if (blockIdx.x == 0) {
        if (threadIdx.x < 64) {
            #pragma unroll
            for (int q = 0; q < 4; q++) {
                int bb = threadIdx.x * 4 + q;
                if (bb != 0) {
                    while (__hip_atomic_load(&flags[bb * 16], __ATOMIC_RELAXED,
                                             __HIP_MEMORY_SCOPE_AGENT) != seq)
                        __builtin_amdgcn_s_sleep(1);
                }
            }
        }
        __syncthreads();
        if (threadIdx.x == 0) {
            __hip_atomic_store(gen, seq, __ATOMIC_RELAXED, __HIP_MEMORY_SCOPE_AGENT);
            __builtin_amdgcn_fence(__ATOMIC_ACQUIRE, "agent");
        }
    } else {
        if (threadIdx.x == 0) {
            __hip_atomic_store(&flags[blockIdx.x * 16], seq, __ATOMIC_RELAXED,
                               __HIP_MEMORY_SCOPE_AGENT);
            while (__hip_atomic_load(gen, __ATOMIC_RELAXED,
                                     __HIP_MEMORY_SCOPE_AGENT) != seq)
                __builtin_amdgcn_s_sleep(2);
            __builtin_amdgcn_fence(__ATOMIC_ACQUIRE, "agent");
        }
    }
    __syncthreads();
}

// Fence-free steady-state barrier (cross-block mutable data is bypass or
// write-once-rotated -> no cache maintenance ever needed).
__device__ __forceinline__ void grid_barrier_nf(unsigned* flags, unsigned* gen, unsigned seq) {
    __syncthreads();
    if (blockIdx.x == 0) {
        if (threadIdx.x < 64) {
            #pragma unroll
            for (int q = 0; q < 4; q++) {
                int bb = threadIdx.x * 4 + q;
                if (bb != 0) {
                    while (__hip_atomic_load(&flags[bb * 16], __ATOMIC_RELAXED,
                                             __HIP_MEMORY_SCOPE_AGENT) != seq)
                        __builtin_amdgcn_s_sleep(1);
                }
            }
        }
        __syncthreads();
        if (threadIdx.x == 0)
            __hip_atomic_store(gen, seq, __ATOMIC_RELAXED, __HIP_MEMORY_SCOPE_AGENT);
    } else {
        if (threadIdx.x == 0) {
            __hip_atomic_store(&flags[blockIdx.x * 16], seq, __ATOMIC_RELAXED,
                               __HIP_MEMORY_SCOPE_AGENT);
            while (__hip_atomic_load(gen, __ATOMIC_RELAXED,
                                     __HIP_MEMORY_SCOPE_AGENT) != seq)
                __builtin_amdgcn_s_sleep(2);
        }
    }
    __syncthreads();
}

__device__ __forceinline__ float sigm(float x) { return 1.f / (1.f + expf(-x)); }

__global__ void __launch_bounds__(NTHR, 4) social_lstm(
    const float* __restrict__ observed,
    const float* __restrict__ W_pos, const float* __restrict__ b_pos,
    const float* __restrict__ W_pool, const float* __restrict__ b_pool,
    const float* __restrict__ Wih_e, const float* __restrict__ bih_e,
    const float* __restrict__ Whh_e, const float* __restrict__ bhh_e,
    const float* __restrict__ Wih_d, const float* __restrict__ bih_d,
    const float* __restrict__ Whh_d, const float* __restrict__ bhh_d,
    const float* __restrict__ W_out, const float* __restrict__ b_out,
    float* __restrict__ out, float* __restrict__ ws, int npred)
{
    extern __shared__ char smem_raw[];
    const int t = threadIdx.x, b = blockIdx.x;
    const int gid = b * NTHR + t;

    unsigned* flags  = (unsigned*)ws;
    unsigned* gen    = flags + 4096;
    unsigned* rtf    = flags + 4112;            // (rt*8+kc)*16
    float* obs     = ws + OFF_OBS;
    float* part    = ws + OFF_PART;
    float* Wt_pool = ws + OFF_WTPOOL;
    float* Wt_ge   = ws + OFF_WTG_E;
    float* Wt_gd   = ws + OFF_WTG_D;
    float* hsbuf   = ws + OFF_HSBUF;
    unsigned seq = 1;

    // ================= init =================
    if (gid < 65536) hsbuf[gid] = 0.f;          // hs[0] = 0
    if (gid < 512) {
        float vx[8], vy[8];
        int fin = 0;
        for (int tt = 0; tt < 8; tt++) {
            float x = observed[tt * 1024 + gid * 2];
            float y = observed[tt * 1024 + gid * 2 + 1];
            vx[tt] = x; vy[tt] = y;
            if (isfinite(x) && isfinite(y)) fin |= (1 << tt);
        }
        int firstv = -1;
        for (int tt = 7; tt >= 0; tt--) if (fin & (1 << tt)) firstv = tt;
        int last = -1;
        for (int tt = 0; tt < 8; tt++) {
            if (fin & (1 << tt)) last = tt;
            int take = (last >= 0) ? last : firstv;
            float ox = 0.f, oy = 0.f;
            if (take >= 0) { ox = vx[take]; oy = vy[take]; }
            obs[tt * 1024 + gid * 2]     = ox;
            obs[tt * 1024 + gid * 2 + 1] = oy;
        }
    }
    if (gid < 65536) {   // Wt_pool[k][p] = W_pool[p][k]
        int p = gid >> 9, k4 = gid & 511;
        float4 v = *(const float4*)(W_pool + p * 2048 + k4 * 4);
        float* dst = Wt_pool + (k4 * 4) * 128 + p;
        dst[0] = v.x; dst[128] = v.y; dst[256] = v.z; dst[384] = v.w;
    }
    if (gid < 163840) {
        int k = gid >> 9, o = gid & 511;
        float ve, vd;
        if (k < 192) { ve = Wih_e[o * 192 + k];       vd = Wih_d[o * 192 + k]; }
        else         { ve = Whh_e[o * 128 + k - 192]; vd = Whh_d[o * 128 + k - 192]; }
        Wt_ge[gid] = ve; Wt_gd[gid] = vd;
    }
    grid_barrier_fenced(flags, gen, seq++);   // one-time flush + invalidate

    const int rt = b >> 3, kc = b & 7, hc = kc;
    const int R0 = rt * 16;
    float cs_reg = 0.f;       // t<256: rl=t>>4, hh=t&15
    const int nstep = 7 + npred;

    for (int s = 0; s < nstep; s++) {
        const float* posp  = (s < 7) ? (obs + (s + 1) * 1024)
                                     : ((s == 7) ? (obs + 7 * 1024) : (out + (s - 8) * 1024));
        const float* prevp = (s < 7) ? (obs + s * 1024)
                                     : ((s <= 8) ? (obs + 7 * 1024) : (out + (s - 9) * 1024));
        const float* Wt_g = (s < 7) ? Wt_ge : Wt_gd;
        const float* bihp = (s < 7) ? bih_e : bih_d;
        const float* bhhp = (s < 7) ? bhh_e : bhh_d;
        const float* hs_r = hsbuf + s * 65536;        // read: CACHED (write-once addresses)
        float*       hs_w = hsbuf + (s + 1) * 65536;  // write: bypass -> MALL

        // ===== Phase AB: pooling (2 cells) + soc GEMM K-chunk =====
        {
            float* pos2 = (float*)smem_raw;                           // 1024 f
            int* cnt    = (int*)(smem_raw + 4096);                    // 32 i
            unsigned short* lst = (unsigned short*)(smem_raw + 4224); // 32*96 us
            float* AsT  = (float*)(smem_raw + 10368);                 // swizzled [256 rows][20]

            if (t < 256) ((float4*)pos2)[t] = ((const float4*)posp)[t];
            if (t < 32) cnt[t] = 0;
            __syncthreads();

            if (kc == 1 && s >= 7 && t < 16) {  // init out row = pos + b_out (bypass)
                int i = R0 + t;
                vf2 v;
                v.x = pos2[2 * i] + b_out[0];
                v.y = pos2[2 * i + 1] + b_out[1];
                st_bypass_f2(out + (s - 7) * 1024 + 2 * i, v);
            }
            {   // pair eval: agent a = t>>6, 64 threads/agent, 8 j each
                int a = t >> 6, i = R0 + a;
                float pix = pos2[2 * i], piy = pos2[2 * i + 1];
                int c0 = kc * 2;
                for (int jj = 0; jj < 8; jj++) {
                    int j = (t & 63) + jj * 64;
                    float dx = pos2[2 * j]     - pix;
                    float dy = pos2[2 * j + 1] - piy;
                    if (j != i && fabsf(dx) <= 1.0f && fabsf(dy) <= 1.0f) {
                        int gx = (int)floorf((dx + 1.0f) * 2.0f); gx = gx < 0 ? 0 : (gx > 3 ? 3 : gx);
                        int gy = (int)floorf((dy + 1.0f) * 2.0f); gy = gy < 0 ? 0 : (gy > 3 ? 3 : gy);
                        int cc = gx * 4 + gy - c0;
                        if (cc == 0 || cc == 1) {
                            int slot = atomicAdd(&cnt[a * 2 + cc], 1);
                            if (slot < 96) lst[(a * 2 + cc) * 96 + slot] = (unsigned short)j;
                        }
                    }
                }
            }
            __syncthreads();
            {   // cell max -> AsT: thread = (a, cc, q4); one float4 per entry, batched
                int a = t >> 6, cc = (t >> 5) & 1, q4 = t & 31;
                int len = cnt[a * 2 + cc]; if (len > 96) len = 96;
                float m[4];
                #pragma unroll
                for (int u = 0; u < 4; u++) m[u] = -3.0e38f;
                const unsigned short* ll = lst + (a * 2 + cc) * 96;
                for (int e = 0; e < len; e += 8) {
                    float4 va[8];
                    #pragma unroll
                    for (int k2 = 0; k2 < 8; k2++) {
                        int ee = e + k2; if (ee >= len) ee = len - 1;   // pad: max idempotent
                        va[k2] = *(const float4*)(hs_r + (int)ll[ee] * 128 + q4 * 4);
                    }
                    #pragma unroll
                    for (int k2 = 0; k2 < 8; k2++) {
                        m[0] = fmaxf(m[0], va[k2].x); m[1] = fmaxf(m[1], va[k2].y);
                        m[2] = fmaxf(m[2], va[k2].z); m[3] = fmaxf(m[3], va[k2].w);
                    }
                }
                #pragma unroll
                for (int u = 0; u < 4; u++)
                    AsT[asr20(cc * 128 + q4 * 4 + u) + a] = (len > 0) ? m[u] : 0.f;
            }
            __syncthreads();
            {   // soc GEMM: 16r x 128o x K256; og32(4c) x ks8 x rowg4; tile 4x4
                int og = (t & 7) | (((t >> 6) & 3) << 3);   // 0..31 (4 cols each)
                int ks = (t >> 3) & 7;
                int rowg = t >> 8;                           // 0..3 (4 rows each)
                float acc[4][4];
                #pragma unroll
                for (int r = 0; r < 4; r++)
                    #pragma unroll
                    for (int o = 0; o < 4; o++) acc[r][o] = 0.f;
                const float4* W4 = (const float4*)Wt_pool;   // L2-resident all steps
                int kb = kc * 256 + ks * 32;
                #pragma unroll 4
                for (int kk = 0; kk < 32; kk++) {
                    int kl = ks * 32 + kk;
                    float4 a4 = *(const float4*)&AsT[asr20(kl) + rowg * 4];
                    float4 w  = W4[(kb + kk) * 32 + og];
                    float ar[4] = {a4.x, a4.y, a4.z, a4.w};
                    float wo[4] = {w.x, w.y, w.z, w.w};
                    #pragma unroll
                    for (int r = 0; r < 4; r++)
                        #pragma unroll
                        for (int o = 0; o < 4; o++)
                            acc[r][o] = fmaf(ar[r], wo[o], acc[r][o]);
                }
                #pragma unroll
                for (int r = 0; r < 4; r++)
                    #pragma unroll
                    for (int o = 0; o < 4; o++) {
                        acc[r][o] += __shfl_xor(acc[r][o], 8);
                        acc[r][o] += __shfl_xor(acc[r][o], 16);
                        acc[r][o] += __shfl_xor(acc[r][o], 32);
                    }
                if ((t & 56) == 0) {   // ks==0 lanes: bypass stores
                    #pragma unroll
                    for (int r = 0; r < 4; r++) {
                        int row = R0 + rowg * 4 + r;
                        float* pp = part + kc * 65536 + row * 128 + og * 4;
                        vf4 v;
                        v.x = acc[r][0]; v.y = acc[r][1]; v.z = acc[r][2]; v.w = acc[r][3];
                        st_bypass_f4(pp, v);
                    }
                }
            }
        }

        // ===== rt-sync (parallel flags) overlapped with CD staging =====
        __syncthreads();                 // drains this block's bypass stores (vmcnt)
        if (t == 0)
            __hip_atomic_store(&rtf[(rt * 8 + kc) * 16], (unsigned)(s + 1),
                               __ATOMIC_RELAXED, __HIP_MEMORY_SCOPE_AGENT);
        {
            float* AsT  = (float*)smem_raw;                 // swizzled [320 rows][20]
            if (t < 512) {   // stage emb rows (k 0..63): independent of part
                int r = t >> 5, e2 = (t & 31) * 2;
                int i2 = 2 * (R0 + r);
                float vx = posp[i2]     - prevp[i2];
                float vy = posp[i2 + 1] - prevp[i2 + 1];
                float e0 = fmaxf(W_pos[e2 * 2]     * vx + W_pos[e2 * 2 + 1] * vy + b_pos[e2],     0.f);
                float e1 = fmaxf(W_pos[e2 * 2 + 2] * vx + W_pos[e2 * 2 + 3] * vy + b_pos[e2 + 1], 0.f);
                AsT[asr20(e2 + 0) + r] = e0;
                AsT[asr20(e2 + 1) + r] = e1;
            } else {         // stage hs rows (k 192..319): cached (L2-hot from gather)
                int t2 = t - 512;
                int r = t2 >> 5, h4 = (t2 & 31) * 4;
                float4 v = *(const float4*)(hs_r + (R0 + r) * 128 + h4);
                AsT[asr20(192 + h4 + 0) + r] = v.x;
                AsT[asr20(192 + h4 + 1) + r] = v.y;
                AsT[asr20(192 + h4 + 2) + r] = v.z;
                AsT[asr20(192 + h4 + 3) + r] = v.w;
            }
            // poll the 8 producer flags in parallel
            if (t < 8) {
                while (__hip_atomic_load(&rtf[(rt * 8 + t) * 16], __ATOMIC_RELAXED,
                                         __HIP_MEMORY_SCOPE_AGENT) != (unsigned)(s + 1))
                    __builtin_amdgcn_s_sleep(1);
            }
            __syncthreads();
            if (t < 512) {   // stage soc rows (k 64..191): bypass part reduce + bias + relu
                int r = t >> 5, p4 = (t & 31) * 4;
                vf4 pv[8];
                ld_bypass_f4x8(part + (R0 + r) * 128 + p4, 65536, pv);
                float sv[4] = {0.f, 0.f, 0.f, 0.f};
                #pragma unroll
                for (int kc2 = 0; kc2 < 8; kc2++) {
                    sv[0] += pv[kc2].x; sv[1] += pv[kc2].y;
                    sv[2] += pv[kc2].z; sv[3] += pv[kc2].w;
                }
                #pragma unroll
                for (int u = 0; u < 4; u++)
                    AsT[asr20(64 + p4 + u) + r] = fmaxf(sv[u] + b_pool[p4 + u], 0.f);
            }
            __syncthreads();
            float* red  = (float*)(smem_raw + 25792);       // [16][64]
            float* hrow = (float*)(smem_raw + 29888);       // [16][16]
            {   // gates GEMM: 16r x 64o x K320; og32(2c) x ks8 x rowg4; tile 4x2
                int og = (t & 7) | (((t >> 6) & 3) << 3);   // 0..31 (2 cols each)
                int ks = (t >> 3) & 7;
                int rowg = t >> 8;
                int gate = og >> 3, loc = og & 7;
                int col2 = gate * 64 + hc * 8 + loc;        // float2 col in Wt_g
                float acc[4][2];
                #pragma unroll
                for (int r = 0; r < 4; r++) { acc[r][0] = 0.f; acc[r][1] = 0.f; }
                const float2* Wg2 = (const float2*)Wt_g;    // L2-resident
                #pragma unroll 4
                for (int kk = 0; kk < 40; kk++) {
                    int k = ks * 40 + kk;
                    float4 a4 = *(const float4*)&AsT[asr20(k) + rowg * 4];
                    float2 w  = Wg2[k * 256 + col2];
                    float ar[4] = {a4.x, a4.y, a4.z, a4.w};
                    #pragma unroll
                    for (int r = 0; r < 4; r++) {
                        acc[r][0] = fmaf(ar[r], w.x, acc[r][0]);
                        acc[r][1] = fmaf(ar[r], w.y, acc[r][1]);
                    }
                }
                #pragma unroll
                for (int r = 0; r < 4; r++)
                    #pragma unroll
                    for (int o = 0; o < 2; o++) {
                        acc[r][o] += __shfl_xor(acc[r][o], 8);
                        acc[r][o] += __shfl_xor(acc[r][o], 16);
                        acc[r][o] += __shfl_xor(acc[r][o], 32);
                    }
                if ((t & 56) == 0) {
                    #pragma unroll
                    for (int r = 0; r < 4; r++)
                        *(float2*)&red[(rowg * 4 + r) * 64 + gate * 16 + loc * 2] =
                            make_float2(acc[r][0], acc[r][1]);
                }
            }
            __syncthreads();
            if (t < 256) {   // pointwise LSTM (mapping unchanged; cs_reg in t<256)
                int rl = t >> 4, hh = t & 15;
                float g4[4];
                #pragma unroll
                for (int q = 0; q < 4; q++) {
                    int colq = q * 128 + hc * 16 + hh;
                    g4[q] = red[rl * 64 + q * 16 + hh] + bihp[colq] + bhhp[colq];
                }
                float si = sigm(g4[0]);
                float sf = sigm(g4[1]);
                float so = sigm(g4[3]);
                float c2 = sf * cs_reg + si * tanhf(g4[2]);
                float h2 = so * tanhf(c2);
                cs_reg = c2;
                hrow[rl * 16 + hh] = h2;
                if (s >= 7) {
                    int i = R0 + rl, h = hc * 16 + hh;
                    float v0 = W_out[h] * h2;
                    float v1 = W_out[128 + h] * h2;
                    v0 += __shfl_down(v0, 8); v0 += __shfl_down(v0, 4);
                    v0 += __shfl_down(v0, 2); v0 += __shfl_down(v0, 1);
                    v1 += __shfl_down(v1, 8); v1 += __shfl_down(v1, 4);
                    v1 += __shfl_down(v1, 2); v1 += __shfl_down(v1, 1);
                    if (hh == 0) {
                        atomicAdd(&out[(s - 7) * 1024 + 2 * i],     v0);
                        atomicAdd(&out[(s - 7) * 1024 + 2 * i + 1], v1);
                    }
                }
            }
            __syncthreads();
            if (t < 64) {   // bypass hs writeback into NEXT rotated buffer (-> MALL)
                int rl = t >> 2, q = t & 3;
                vf4 v;
                v.x = hrow[rl * 16 + q * 4 + 0];
                v.y = hrow[rl * 16 + q * 4 + 1];
                v.z = hrow[rl * 16 + q * 4 + 2];
                v.w = hrow[rl * 16 + q * 4 + 3];
                st_bypass_f4(hs_w + (R0 + rl) * 128 + hc * 16 + q * 4, v);
            }
        }
        grid_barrier_nf(flags, gen, seq++);   // fence-free
    }
}

extern "C" void kernel_launch(void* const* d_in, const int* in_sizes, int n_in,
                              void* d_out, int out_size, void* d_ws, size_t ws_size,
                              hipStream_t stream) {
    const float* observed = (const float*)d_in[0];
    const float* W_pos    = (const float*)d_in[1];
    const float* b_pos    = (const float*)d_in[2];
    const float* W_pool   = (const float*)d_in[3];
    const float* b_pool   = (const float*)d_in[4];
    const float* Wih_e    = (const float*)d_in[5];
    const float* bih_e    = (const float*)d_in[6];
    const float* Whh_e    = (const float*)d_in[7];
    const float* bhh_e    = (const float*)d_in[8];
    const float* Wih_d    = (const float*)d_in[9];
    const float* bih_d    = (const float*)d_in[10];
    const float* Whh_d    = (const float*)d_in[11];
    const float* bhh_d    = (const float*)d_in[12];
    const float* W_out    = (const float*)d_in[13];
    const float* b_out    = (const float*)d_in[14];
    float* outp = (float*)d_out;
    float* wsp  = (float*)d_ws;
    int npred = out_size / 1024;

    hipMemsetAsync(d_ws, 0, 33024, stream);   // arrival flags + gen + rt flags

    social_lstm<<<NBLK, NTHR, LDS_BYTES, stream>>>(
        observed, W_pos, b_pos, W_pool, b_pool,
        Wih_e, bih_e, Whh_e, bhh_e,
        Wih_d, bih_d, Whh_d, bhh_d,
        W_out, b_out, outp, wsp, npred);
}